// Round 4
// baseline (362.026 us; speedup 1.0000x reference)
//
#include <hip/hip_runtime.h>

#define NB 8
#define NC 21
#define NCC (NC * NC)                            // 441
#define HW (512 * 512)
#define BLOCKS_PER_SAMPLE 256                    // 1024 pixels per block
#define PIX_PER_BLOCK (HW / BLOCKS_PER_SAMPLE)   // 1024
#define THREADS 256                              // 1 float4 (4 pixels) per thread
#define RMAX 64                                  // confusion-matrix replicas

// R4 theory: the 115 us floor (invariant to warm/cold L3, ILP, occupancy)
// was global-atomic contention: 2048 blocks x 441 atomicAdds into the SAME
// 221 cache lines = 32.7K serialized same-line far-atomics per line
// (~3.5 ns each ~= 115 us). Fix: 64 replica slices; block uses replica
// blockIdx&63 -- XCD mapping is blockIdx%8 round-robin, so each replica is
// only touched by one XCD (no cross-XCD line ping-pong) and per-line chains
// drop 64x. Loads revert to the simple rolling-max (VGPR ~32; R1-R3 proved
// codegen batching never materializes), and (256,8) makes all 8 blocks/CU
// co-resident (32 waves/CU) so TLP covers load latency once atomics are gone.
__global__ __launch_bounds__(THREADS, 8) void conf_kernel(
    const float* __restrict__ pred,
    const float* __restrict__ targ,
    int* __restrict__ rep /* [R][NB][NCC] */, int rmask) {
  __shared__ int lconf[NCC];
  const int tid = threadIdx.x;
  for (int i = tid; i < NCC; i += THREADS) lconf[i] = 0;
  __syncthreads();

  const int b   = blockIdx.x / BLOCKS_PER_SAMPLE;
  const int blk = blockIdx.x % BLOCKS_PER_SAMPLE;
  const float* __restrict__ pbase = pred + (size_t)b * NC * HW;
  const float* __restrict__ tbase = targ + (size_t)b * NC * HW;
  const int p0 = blk * PIX_PER_BLOCK + tid * 4;  // 16B-aligned

  // channel 0 init
  float4 bp = *(const float4*)(pbase + p0);
  float4 bt = *(const float4*)(tbase + p0);
  int ip0 = 0, ip1 = 0, ip2 = 0, ip3 = 0;
  int it0 = 0, it1 = 0, it2 = 0, it3 = 0;
#pragma unroll
  for (int c = 1; c < NC; ++c) {
    float4 vp = *(const float4*)(pbase + (size_t)c * HW + p0);
    float4 vt = *(const float4*)(tbase + (size_t)c * HW + p0);
    if (vp.x > bp.x) { bp.x = vp.x; ip0 = c; }
    if (vp.y > bp.y) { bp.y = vp.y; ip1 = c; }
    if (vp.z > bp.z) { bp.z = vp.z; ip2 = c; }
    if (vp.w > bp.w) { bp.w = vp.w; ip3 = c; }
    if (vt.x > bt.x) { bt.x = vt.x; it0 = c; }
    if (vt.y > bt.y) { bt.y = vt.y; it1 = c; }
    if (vt.z > bt.z) { bt.z = vt.z; it2 = c; }
    if (vt.w > bt.w) { bt.w = vt.w; it3 = c; }
  }
  atomicAdd(&lconf[it0 * NC + ip0], 1);
  atomicAdd(&lconf[it1 * NC + ip1], 1);
  atomicAdd(&lconf[it2 * NC + ip2], 1);
  atomicAdd(&lconf[it3 * NC + ip3], 1);
  __syncthreads();

  // flush into this block's replica slice (shared by one XCD only)
  int* __restrict__ gconf = rep + ((size_t)(blockIdx.x & rmask) * NB + b) * NCC;
  for (int i = tid; i < NCC; i += THREADS) {
    int v = lconf[i];
    if (v) atomicAdd(&gconf[i], v);
  }
}

// Sum the R replica slices into the final conf. Coalesced: consecutive
// threads read consecutive ints within each replica slice.
__global__ __launch_bounds__(256) void reduce_kernel(
    const int* __restrict__ rep, int* __restrict__ conf, int R) {
  const int o = blockIdx.x * 256 + threadIdx.x;
  if (o < NB * NCC) {
    int s = 0;
    for (int r = 0; r < R; ++r) s += rep[(size_t)r * NB * NCC + o];
    conf[o] = s;
  }
}

// conf -> per-class IoU -> per-sample mean over valid classes -> batch mean.
__global__ __launch_bounds__(256) void iou_kernel(const int* __restrict__ conf,
                                                  float* __restrict__ out) {
  __shared__ float iou_sum[NB];
  __shared__ int valid_cnt[NB];
  const int tid = threadIdx.x;
  if (tid < NB) { iou_sum[tid] = 0.f; valid_cnt[tid] = 0; }
  __syncthreads();

  if (tid < NB * NC) {
    const int b = tid / NC, c = tid % NC;
    const int* __restrict__ m = conf + b * NCC;
    const int tp = m[c * NC + c];
    int row = 0, col = 0;
#pragma unroll
    for (int j = 0; j < NC; ++j) {
      row += m[c * NC + j];  // TP + FN
      col += m[j * NC + c];  // TP + FP
    }
    if (tp > 0) {
      const float denom = (float)(row + col - tp);  // TP + FN + FP
      atomicAdd(&iou_sum[b], (float)tp / denom);
      atomicAdd(&valid_cnt[b], 1);
    }
  }
  __syncthreads();

  if (tid == 0) {
    float s = 0.f;
    for (int b = 0; b < NB; ++b) {
      const int n = valid_cnt[b] > 0 ? valid_cnt[b] : 1;
      s += iou_sum[b] / (float)n;
    }
    out[0] = s / (float)NB;
  }
}

extern "C" void kernel_launch(void* const* d_in, const int* in_sizes, int n_in,
                              void* d_out, int out_size, void* d_ws, size_t ws_size,
                              hipStream_t stream) {
  const float* pred = (const float*)d_in[0];
  const float* targ = (const float*)d_in[1];
  float* out = (float*)d_out;

  // Pick the largest replica count that fits the workspace: R slices + final.
  int R = RMAX;
  while (R > 1 &&
         (size_t)(R + 1) * NB * NCC * sizeof(int) > ws_size) R >>= 1;
  int* rep = (int*)d_ws;
  int* conf;
  if ((size_t)(R + 1) * NB * NCC * sizeof(int) <= ws_size) {
    conf = rep + (size_t)R * NB * NCC;
  } else {
    conf = rep;  // R==1 degenerate fallback: accumulate directly, skip reduce
  }

  hipMemsetAsync(rep, 0, (size_t)R * NB * NCC * sizeof(int), stream);
  conf_kernel<<<NB * BLOCKS_PER_SAMPLE, THREADS, 0, stream>>>(pred, targ, rep,
                                                              R - 1);
  if (conf != rep) {
    reduce_kernel<<<(NB * NCC + 255) / 256, 256, 0, stream>>>(rep, conf, R);
  }
  iou_kernel<<<1, 256, 0, stream>>>(conf, out);
}

// Round 5
// 351.774 us; speedup vs baseline: 1.0291x; 1.0291x over previous
//
#include <hip/hip_runtime.h>

#define NB 8
#define NC 21
#define NCC (NC * NC)                            // 441
#define HW (512 * 512)
#define THREADS 256
#define PPT 8                                    // pixels per thread: 2 float4 groups
#define PIX_PER_BLOCK (THREADS * PPT)            // 2048
#define BLOCKS_PER_SAMPLE (HW / PIX_PER_BLOCK)   // 128
#define GSTRIDE (THREADS * 4)                    // 1024 floats between groups

// R5: pixel-group ILP + manual channel double-buffer.
// R0-R3 proved channel-batching always collapses back to ~2 loads in flight
// (VGPR 32/40/48, dur pinned 115-121 us): the 21 loads all feed ONE rolling
// accumulator, so the scheduler sinks them to minimize pressure. R4 proved
// it isn't global-atomic contention either. Delivered BW is stuck at 2.9
// TB/s ~= 4 KB in flight per CU -- a pure MLP shortfall.
// Fix: 2 INDEPENDENT pixel groups per thread (separate max/idx state) and a
// rotated next-channel register buffer: next loads have no dependence on
// current compares and stay live across them, forcing ~8 loads in flight
// per wave (x16 waves/CU = 64 KB/CU) and an 8 KB contiguous sweep per block
// per channel step.
__global__ __launch_bounds__(THREADS, 4) void conf_kernel(
    const float* __restrict__ pred,
    const float* __restrict__ targ,
    int* __restrict__ conf /* [NB][NCC] */) {
  __shared__ int lconf[NCC];
  const int tid = threadIdx.x;
  for (int i = tid; i < NCC; i += THREADS) lconf[i] = 0;
  __syncthreads();

  const int b   = blockIdx.x / BLOCKS_PER_SAMPLE;
  const int blk = blockIdx.x % BLOCKS_PER_SAMPLE;
  const int p0  = blk * PIX_PER_BLOCK + tid * 4;  // group 0 float index
  const float* __restrict__ pb = pred + (size_t)b * NC * HW + p0;
  const float* __restrict__ tb = targ + (size_t)b * NC * HW + p0;

#define LD(base, c, g) (*(const float4*)((base) + (size_t)(c) * HW + (g) * GSTRIDE))

  // ---- c = 0: init state for both groups, both tensors ----
  float4 mp0 = LD(pb, 0, 0), mp1 = LD(pb, 0, 1);
  float4 mt0 = LD(tb, 0, 0), mt1 = LD(tb, 0, 1);
  int ip00 = 0, ip01 = 0, ip02 = 0, ip03 = 0;
  int ip10 = 0, ip11 = 0, ip12 = 0, ip13 = 0;
  int it00 = 0, it01 = 0, it02 = 0, it03 = 0;
  int it10 = 0, it11 = 0, it12 = 0, it13 = 0;

  // prologue: c = 1 in flight
  float4 np0 = LD(pb, 1, 0), np1 = LD(pb, 1, 1);
  float4 nt0 = LD(tb, 1, 0), nt1 = LD(tb, 1, 1);

#define UPD(m, i0, i1, i2, i3, v, c)              \
  do {                                            \
    if ((v).x > (m).x) { (m).x = (v).x; i0 = c; } \
    if ((v).y > (m).y) { (m).y = (v).y; i1 = c; } \
    if ((v).z > (m).z) { (m).z = (v).z; i2 = c; } \
    if ((v).w > (m).w) { (m).w = (v).w; i3 = c; } \
  } while (0)

#pragma unroll
  for (int c = 1; c < NC; ++c) {
    // consume current, rotate
    const float4 qp0 = np0, qp1 = np1, qt0 = nt0, qt1 = nt1;
    if (c + 1 < NC) {  // issue next-channel loads (no dep on compares below)
      np0 = LD(pb, c + 1, 0);
      np1 = LD(pb, c + 1, 1);
      nt0 = LD(tb, c + 1, 0);
      nt1 = LD(tb, c + 1, 1);
    }
    UPD(mp0, ip00, ip01, ip02, ip03, qp0, c);
    UPD(mp1, ip10, ip11, ip12, ip13, qp1, c);
    UPD(mt0, it00, it01, it02, it03, qt0, c);
    UPD(mt1, it10, it11, it12, it13, qt1, c);
  }
#undef UPD
#undef LD

  atomicAdd(&lconf[it00 * NC + ip00], 1);
  atomicAdd(&lconf[it01 * NC + ip01], 1);
  atomicAdd(&lconf[it02 * NC + ip02], 1);
  atomicAdd(&lconf[it03 * NC + ip03], 1);
  atomicAdd(&lconf[it10 * NC + ip10], 1);
  atomicAdd(&lconf[it11 * NC + ip11], 1);
  atomicAdd(&lconf[it12 * NC + ip12], 1);
  atomicAdd(&lconf[it13 * NC + ip13], 1);
  __syncthreads();

  int* __restrict__ gconf = conf + b * NCC;
  for (int i = tid; i < NCC; i += THREADS) {
    int v = lconf[i];
    if (v) atomicAdd(&gconf[i], v);
  }
}

// conf -> per-class IoU -> per-sample mean over valid classes -> batch mean.
__global__ __launch_bounds__(256) void iou_kernel(const int* __restrict__ conf,
                                                  float* __restrict__ out) {
  __shared__ float iou_sum[NB];
  __shared__ int valid_cnt[NB];
  const int tid = threadIdx.x;
  if (tid < NB) { iou_sum[tid] = 0.f; valid_cnt[tid] = 0; }
  __syncthreads();

  if (tid < NB * NC) {
    const int b = tid / NC, c = tid % NC;
    const int* __restrict__ m = conf + b * NCC;
    const int tp = m[c * NC + c];
    int row = 0, col = 0;
#pragma unroll
    for (int j = 0; j < NC; ++j) {
      row += m[c * NC + j];  // TP + FN
      col += m[j * NC + c];  // TP + FP
    }
    if (tp > 0) {
      const float denom = (float)(row + col - tp);  // TP + FN + FP
      atomicAdd(&iou_sum[b], (float)tp / denom);
      atomicAdd(&valid_cnt[b], 1);
    }
  }
  __syncthreads();

  if (tid == 0) {
    float s = 0.f;
    for (int b = 0; b < NB; ++b) {
      const int n = valid_cnt[b] > 0 ? valid_cnt[b] : 1;
      s += iou_sum[b] / (float)n;
    }
    out[0] = s / (float)NB;
  }
}

extern "C" void kernel_launch(void* const* d_in, const int* in_sizes, int n_in,
                              void* d_out, int out_size, void* d_ws, size_t ws_size,
                              hipStream_t stream) {
  const float* pred = (const float*)d_in[0];
  const float* targ = (const float*)d_in[1];
  float* out = (float*)d_out;
  int* conf = (int*)d_ws;  // NB*NCC ints = 14112 B

  hipMemsetAsync(conf, 0, NB * NCC * sizeof(int), stream);
  conf_kernel<<<NB * BLOCKS_PER_SAMPLE, THREADS, 0, stream>>>(pred, targ, conf);
  iou_kernel<<<1, 256, 0, stream>>>(conf, out);
}